// Round 1
// baseline (3005.723 us; speedup 1.0000x reference)
//
#include <hip/hip_runtime.h>
#include <hip/hip_fp16.h>

#define B_    128
#define T_    1024
#define H_    256
#define G4    1024
#define NTH   512
#define NREG  104   // f16 column-pairs per row held in VGPRs
#define NLDS  24    // f16 column-pairs per row held in LDS (NREG+NLDS==128)

typedef _Float16 half2_t __attribute__((ext_vector_type(2)));

__device__ __forceinline__ float fdot2(unsigned int w, unsigned int h, float acc) {
    return __builtin_amdgcn_fdot2(__builtin_bit_cast(half2_t, w),
                                  __builtin_bit_cast(half2_t, h), acc, false);
}
__device__ __forceinline__ unsigned int packf16(float a, float b) {
    half2_t h;
    h.x = (_Float16)a;
    h.y = (_Float16)b;
    return __builtin_bit_cast(unsigned int, h);
}

// ---------------------------------------------------------------------------
// Kernel 1: persistent LSTM. 1 block per batch element, 512 threads.
// Thread t owns gate rows t and t+512. Row weights: 104 f16-pairs in VGPRs,
// 24 f16-pairs in LDS. h broadcast from LDS as f16 pairs; fp32 c-state.
// Writes last 512 hidden states transposed: hT[(t'*256+u)*128 + b].
// ---------------------------------------------------------------------------
__global__ __launch_bounds__(NTH, 2) void lstm_k(
    const float* __restrict__ x, const float* __restrict__ w_ih,
    const float* __restrict__ w_hh, const float* __restrict__ b_ih,
    const float* __restrict__ b_hh, float* __restrict__ hT) {
    extern __shared__ unsigned char smem_raw[];
    unsigned int* w_lds = (unsigned int*)smem_raw;                    // [NLDS][1024]
    unsigned int* h_lds = (unsigned int*)(smem_raw + NLDS * G4 * 4);  // [128] f16x2
    float* gates = (float*)(smem_raw + NLDS * G4 * 4 + 512);          // [1024]
    float* xseq  = (float*)(smem_raw + NLDS * G4 * 4 + 512 + 4096);   // [1024]

    const int tid = threadIdx.x;
    const int b   = blockIdx.x;
    const int r0  = tid, r1 = tid + NTH;

    const float bsum0 = b_ih[r0] + b_hh[r0], wi0 = w_ih[r0];
    const float bsum1 = b_ih[r1] + b_hh[r1], wi1 = w_ih[r1];

    // xseq[t] = x[b, (t%512)*2 + t/512]   (reshape+moveaxis of reference)
    for (int t = tid; t < T_; t += NTH)
        xseq[t] = x[b * T_ + ((t & 511) << 1) + (t >> 9)];

    // register-resident weights (f16 pairs), columns [0, 2*NREG)
    unsigned int wr0[NREG], wr1[NREG];
#pragma unroll
    for (int p = 0; p < NREG; ++p) {
        float2 a = *(const float2*)&w_hh[r0 * H_ + 2 * p];
        wr0[p] = packf16(a.x, a.y);
        float2 c = *(const float2*)&w_hh[r1 * H_ + 2 * p];
        wr1[p] = packf16(c.x, c.y);
    }
    // LDS-resident weights, columns [2*NREG, 256), layout [pair][row]
    for (int idx = tid; idx < NLDS * G4; idx += NTH) {
        int q = idx >> 10, r = idx & (G4 - 1);
        float2 a = *(const float2*)&w_hh[r * H_ + 2 * (NREG + q)];
        w_lds[idx] = packf16(a.x, a.y);
    }
    if (tid < 128) h_lds[tid] = 0u;
    float c_state = 0.f;
    __syncthreads();

    for (int t = 0; t < T_; ++t) {
        const float xt = xseq[t];
        float a0 = fmaf(xt, wi0, bsum0);
        float a1 = fmaf(xt, wi1, bsum1);
#pragma unroll
        for (int g = 0; g < NREG / 4; ++g) {
            uint4 hp = *(const uint4*)&h_lds[g * 4];  // broadcast b128
            a0 = fdot2(wr0[4 * g + 0], hp.x, a0); a1 = fdot2(wr1[4 * g + 0], hp.x, a1);
            a0 = fdot2(wr0[4 * g + 1], hp.y, a0); a1 = fdot2(wr1[4 * g + 1], hp.y, a1);
            a0 = fdot2(wr0[4 * g + 2], hp.z, a0); a1 = fdot2(wr1[4 * g + 2], hp.z, a1);
            a0 = fdot2(wr0[4 * g + 3], hp.w, a0); a1 = fdot2(wr1[4 * g + 3], hp.w, a1);
        }
#pragma unroll
        for (int g = 0; g < NLDS / 4; ++g) {
            uint4 hp = *(const uint4*)&h_lds[NREG + g * 4];
#pragma unroll
            for (int q = 0; q < 4; ++q) {
                unsigned int wl0 = w_lds[(g * 4 + q) * G4 + r0];  // lane-consecutive
                unsigned int wl1 = w_lds[(g * 4 + q) * G4 + r1];
                unsigned int hq = (&hp.x)[q];
                a0 = fdot2(wl0, hq, a0);
                a1 = fdot2(wl1, hq, a1);
            }
        }
        gates[r0] = a0;
        gates[r1] = a1;
        __syncthreads();
        if (tid < H_) {
            float gi = gates[tid], gf = gates[tid + 256];
            float gg = gates[tid + 512], go = gates[tid + 768];
            float i_ = __builtin_amdgcn_rcpf(1.f + __expf(-gi));
            float f_ = __builtin_amdgcn_rcpf(1.f + __expf(-gf));
            float g_ = 1.f - 2.f * __builtin_amdgcn_rcpf(__expf(2.f * gg) + 1.f);
            float o_ = __builtin_amdgcn_rcpf(1.f + __expf(-go));
            c_state = f_ * c_state + i_ * g_;
            float h = o_ * (1.f - 2.f * __builtin_amdgcn_rcpf(__expf(2.f * c_state) + 1.f));
            reinterpret_cast<__half*>(h_lds)[tid] = __float2half(h);
            if (t >= 512)
                hT[(size_t)(((t - 512) << 8) + tid) * B_ + b] = h;
        }
        __syncthreads();
    }
}

// ---------------------------------------------------------------------------
// Kernel 2: res1 partials. out[b][m] partial over n-chunk.
// grid (4 m-blocks of 64, 64 k-chunks of 2048), 256 threads.
// Lanes carry b (coalesced hT reads); w1 values wave-uniform (scalar loads).
// part layout: part[(ks*256 + m)*128 + b]
// ---------------------------------------------------------------------------
__global__ __launch_bounds__(256, 4) void gemm1_k(
    const float* __restrict__ hT, const float* __restrict__ w1,
    float* __restrict__ part) {
    const int tid = threadIdx.x;
    const int mb  = blockIdx.x;  // 0..3
    const int ks  = blockIdx.y;  // 0..63
    const int bl  = tid & 127;
    const int mg  = __builtin_amdgcn_readfirstlane(tid >> 7);
    const int mbase = mb * 64 + mg * 32;

    float acc[32];
#pragma unroll
    for (int j = 0; j < 32; ++j) acc[j] = 0.f;

    const int n0beg = ks * 2048;
    for (int n0 = n0beg; n0 < n0beg + 2048; n0 += 8) {
        float hv[8];
#pragma unroll
        for (int q = 0; q < 8; ++q) hv[q] = hT[(size_t)(n0 + q) * B_ + bl];
#pragma unroll
        for (int j = 0; j < 32; ++j) {
            const float* wr = &w1[(size_t)(mbase + j) * 131072 + n0];
#pragma unroll
            for (int q = 0; q < 8; ++q) acc[j] = fmaf(hv[q], wr[q], acc[j]);
        }
    }
#pragma unroll
    for (int j = 0; j < 32; ++j)
        part[(size_t)(ks * 256 + mbase + j) * B_ + bl] = acc[j];
}

// ---------------------------------------------------------------------------
// Kernel 3: reduce partials (+b1, ReLU) -> res1 ; res2 = res1@w2.T+b2 ;
// res3 = res2@w3.T+b3 -> out.  1 block per batch row, 512 threads.
// ---------------------------------------------------------------------------
__global__ __launch_bounds__(512, 2) void head_k(
    const float* __restrict__ part, const float* __restrict__ b1,
    const float* __restrict__ w2, const float* __restrict__ b2,
    const float* __restrict__ w3, const float* __restrict__ b3,
    float* __restrict__ out) {
    __shared__ float res1[256];
    __shared__ float res2[512];
    const int tid = threadIdx.x;
    const int b   = blockIdx.x;

    if (tid < 256) {
        float s = b1[tid];
#pragma unroll 8
        for (int ks = 0; ks < 64; ++ks)
            s += part[(size_t)(ks * 256 + tid) * B_ + b];
        res1[tid] = fmaxf(s, 0.f);
    }
    __syncthreads();
    {
        float s = b2[tid];
        const float* wr = &w2[tid * 256];
#pragma unroll 4
        for (int k = 0; k < 256; k += 4) {
            float4 w = *(const float4*)&wr[k];
            s += res1[k] * w.x + res1[k + 1] * w.y + res1[k + 2] * w.z + res1[k + 3] * w.w;
        }
        res2[tid] = s;
    }
    __syncthreads();
    if (tid < 64) {
        float s = b3[tid];
        const float* wr = &w3[tid * 512];
#pragma unroll 4
        for (int k = 0; k < 512; k += 4) {
            float4 w = *(const float4*)&wr[k];
            s += res2[k] * w.x + res2[k + 1] * w.y + res2[k + 2] * w.z + res2[k + 3] * w.w;
        }
        out[b * 64 + tid] = s;
    }
}

extern "C" void kernel_launch(void* const* d_in, const int* in_sizes, int n_in,
                              void* d_out, int out_size, void* d_ws, size_t ws_size,
                              hipStream_t stream) {
    (void)in_sizes; (void)n_in; (void)out_size; (void)ws_size;
    const float* x    = (const float*)d_in[0];
    const float* w_ih = (const float*)d_in[1];
    const float* w_hh = (const float*)d_in[2];
    const float* b_ih = (const float*)d_in[3];
    const float* b_hh = (const float*)d_in[4];
    const float* w1   = (const float*)d_in[5];
    const float* b1   = (const float*)d_in[6];
    const float* w2   = (const float*)d_in[7];
    const float* b2   = (const float*)d_in[8];
    const float* w3   = (const float*)d_in[9];
    const float* b3   = (const float*)d_in[10];
    float* out  = (float*)d_out;
    float* hT   = (float*)d_ws;                                    // 131072*128 f32 = 64 MB
    float* part = (float*)((char*)d_ws + (size_t)131072 * 128 * 4); // 64*256*128 f32 = 8 MB

    const size_t smem1 = (size_t)NLDS * G4 * 4 + 512 + 4096 + 4096;  // 107,008 B
    hipFuncSetAttribute((const void*)lstm_k,
                        hipFuncAttributeMaxDynamicSharedMemorySize, (int)smem1);

    hipLaunchKernelGGL(lstm_k, dim3(B_), dim3(NTH), smem1, stream,
                       x, w_ih, w_hh, b_ih, b_hh, hT);
    hipLaunchKernelGGL(gemm1_k, dim3(4, 64), dim3(256), 0, stream, hT, w1, part);
    hipLaunchKernelGGL(head_k, dim3(B_), dim3(512), 0, stream,
                       part, b1, w2, b2, w3, b3, out);
}

// Round 3
// 2971.038 us; speedup vs baseline: 1.0117x; 1.0117x over previous
//
#include <hip/hip_runtime.h>
#include <hip/hip_fp16.h>

#define B_    128
#define T_    1024
#define H_    256
#define NTH   512
#define NREG  96            // f16 column-pairs per row in VGPRs
#define NLDS  32            // f16 column-pairs per row in LDS
#define NQR   (NREG / 4)    // 24 h-quads consumed by register part
#define NQL   (NLDS / 4)    // 8 h-quads consumed by LDS part

typedef _Float16 half2_t __attribute__((ext_vector_type(2)));

__device__ __forceinline__ float fdot2(unsigned int w, unsigned int h, float acc) {
    return __builtin_amdgcn_fdot2(__builtin_bit_cast(half2_t, w),
                                  __builtin_bit_cast(half2_t, h), acc, false);
}
__device__ __forceinline__ unsigned int packf16(float a, float b) {
    half2_t h;
    h.x = (_Float16)a;
    h.y = (_Float16)b;
    return __builtin_bit_cast(unsigned int, h);
}

// ---------------------------------------------------------------------------
// Kernel 1: persistent LSTM. 1 block/batch, 512 threads, thread owns gate
// rows r0=tid, r1=tid+512. 96 weight pairs/row in VGPR, 32 pairs/row in LDS
// (uint4 groups, XOR-swizzled: slot = g ^ (row&7) -> conflict-free b128).
// 4 independent dot chains/thread. h kept as packed f16 pairs in LDS.
// Last 512 steps written as hT_p[(t'*128 + p)*128 + b] = packed pair.
// ---------------------------------------------------------------------------
__global__ __launch_bounds__(NTH, 2) void lstm_k(
    const float* __restrict__ x, const float* __restrict__ w_ih,
    const float* __restrict__ w_hh, const float* __restrict__ b_ih,
    const float* __restrict__ b_hh, unsigned int* __restrict__ hT_p) {
    extern __shared__ unsigned char smem[];
    uint4*        w_lds4 = (uint4*)smem;                           // [1024][8] = 128 KB
    unsigned int* h_u32  = (unsigned int*)(smem + 131072);         // [128] packed pairs
    __half*       h_half = (__half*)(smem + 131072);               // alias, [256]
    float*        gates4 = (float*)(smem + 131072 + 512);          // [256][4]
    float*        xseq   = (float*)(smem + 131072 + 512 + 4096);   // [1024]

    const int tid = threadIdx.x;
    const int b   = blockIdx.x;
    const int r0  = tid, r1 = tid + NTH;
    const int u   = tid & 255;          // unit
    const int g0  = tid >> 8;           // 0:i 1:f ; r1 -> 2:g 3:o
    const int s0  = r0 & 7, s1 = r1 & 7;

    const float bs0 = b_ih[r0] + b_hh[r0], wi0 = w_ih[r0];
    const float bs1 = b_ih[r1] + b_hh[r1], wi1 = w_ih[r1];

    // xseq[t] = x[b, (t%512)*2 + t/512]
    for (int t = tid; t < T_; t += NTH)
        xseq[t] = x[b * T_ + ((t & 511) << 1) + (t >> 9)];

    // register weights: columns [0, 192)
    unsigned int wr0[NREG], wr1[NREG];
#pragma unroll
    for (int p = 0; p < NREG; p += 2) {
        float4 a = *(const float4*)&w_hh[r0 * H_ + 2 * p];
        wr0[p] = packf16(a.x, a.y); wr0[p + 1] = packf16(a.z, a.w);
        float4 c = *(const float4*)&w_hh[r1 * H_ + 2 * p];
        wr1[p] = packf16(c.x, c.y); wr1[p + 1] = packf16(c.z, c.w);
    }
    // LDS weights: columns [192, 256), uint4 per (row, g), XOR-swizzled slot
    for (int idx = tid; idx < 1024 * NQL; idx += NTH) {
        int row = idx >> 3, g = idx & 7;
        const float4* src = (const float4*)&w_hh[row * H_ + 2 * NREG + g * 8];
        float4 a = src[0], c = src[1];
        uint4 pk;
        pk.x = packf16(a.x, a.y); pk.y = packf16(a.z, a.w);
        pk.z = packf16(c.x, c.y); pk.w = packf16(c.z, c.w);
        w_lds4[(row << 3) | (g ^ (row & 7))] = pk;
    }
    if (tid < 128) h_u32[tid] = 0u;
    float c_state = 0.f;
    __syncthreads();

    const uint4* h4 = (const uint4*)h_u32;

    for (int t = 0; t < T_; ++t) {
        const float xt = xseq[t];
        float a00 = fmaf(xt, wi0, bs0), a01 = 0.f;   // row r0: 2 chains
        float a10 = fmaf(xt, wi1, bs1), a11 = 0.f;   // row r1: 2 chains
#pragma unroll
        for (int q = 0; q < NQR; ++q) {
            uint4 hp = h4[q];
            a00 = fdot2(wr0[4 * q + 0], hp.x, a00);
            a01 = fdot2(wr0[4 * q + 1], hp.y, a01);
            a10 = fdot2(wr1[4 * q + 0], hp.x, a10);
            a11 = fdot2(wr1[4 * q + 1], hp.y, a11);
            a00 = fdot2(wr0[4 * q + 2], hp.z, a00);
            a01 = fdot2(wr0[4 * q + 3], hp.w, a01);
            a10 = fdot2(wr1[4 * q + 2], hp.z, a10);
            a11 = fdot2(wr1[4 * q + 3], hp.w, a11);
        }
#pragma unroll
        for (int q = 0; q < NQL; ++q) {
            uint4 hp = h4[NQR + q];
            uint4 w0 = w_lds4[(r0 << 3) | (q ^ s0)];
            uint4 w1 = w_lds4[(r1 << 3) | (q ^ s1)];
            a00 = fdot2(w0.x, hp.x, a00);
            a01 = fdot2(w0.y, hp.y, a01);
            a10 = fdot2(w1.x, hp.x, a10);
            a11 = fdot2(w1.y, hp.y, a11);
            a00 = fdot2(w0.z, hp.z, a00);
            a01 = fdot2(w0.w, hp.w, a01);
            a10 = fdot2(w1.z, hp.z, a10);
            a11 = fdot2(w1.w, hp.w, a11);
        }
        gates4[(u << 2) | g0]       = a00 + a01;
        gates4[(u << 2) | (g0 + 2)] = a10 + a11;
        __syncthreads();
        if (tid < H_) {
            const float4 g4 = *(const float4*)&gates4[tid << 2];
            float i_ = __builtin_amdgcn_rcpf(1.f + __expf(-g4.x));
            float f_ = __builtin_amdgcn_rcpf(1.f + __expf(-g4.y));
            float g_ = 1.f - 2.f * __builtin_amdgcn_rcpf(__expf(2.f * g4.z) + 1.f);
            float o_ = __builtin_amdgcn_rcpf(1.f + __expf(-g4.w));
            c_state = f_ * c_state + i_ * g_;
            float h = o_ * (1.f - 2.f * __builtin_amdgcn_rcpf(__expf(2.f * c_state) + 1.f));
            h_half[tid] = __float2half(h);
        }
        __syncthreads();
        if (t >= 512 && tid < 128)
            hT_p[(size_t)(((t - 512) << 7) + tid) * B_ + b] = h_u32[tid];
    }
}

// ---------------------------------------------------------------------------
// Kernel 2: res1 partials. grid (4 m-blocks of 64, 256 k-chunks of 256 pairs),
// 256 threads. Lanes carry b (coalesced packed-h loads); w1 stays fp32,
// wave-uniform scalar loads. part[(kc*256 + m)*128 + b].
// ---------------------------------------------------------------------------
__global__ __launch_bounds__(256, 4) void gemm1_k(
    const unsigned int* __restrict__ hT_p, const float* __restrict__ w1,
    float* __restrict__ part) {
    const int tid = threadIdx.x;
    const int mb  = blockIdx.x;          // 0..3
    const int kc  = blockIdx.y;          // 0..255
    const int bl  = tid & 127;
    const int mg  = __builtin_amdgcn_readfirstlane(tid >> 7);
    const int mbase = mb * 64 + mg * 32;

    float acc[32];
#pragma unroll
    for (int j = 0; j < 32; ++j) acc[j] = 0.f;

    const int k0 = kc * 256;
#pragma unroll 2
    for (int kp = 0; kp < 256; ++kp) {
        const int k = k0 + kp;
        unsigned int hp = hT_p[(size_t)k * B_ + bl];
        half2_t hv = __builtin_bit_cast(half2_t, hp);
        float h0 = (float)hv.x, h1 = (float)hv.y;
#pragma unroll
        for (int j = 0; j < 32; ++j) {
            const float2 w = *(const float2*)&w1[(size_t)(mbase + j) * 131072 + 2 * k];
            acc[j] = fmaf(h0, w.x, fmaf(h1, w.y, acc[j]));
        }
    }
#pragma unroll
    for (int j = 0; j < 32; ++j)
        part[(size_t)(kc * 256 + mbase + j) * B_ + bl] = acc[j];
}

// ---------------------------------------------------------------------------
// Kernel 3: reduce partials over 256 k-chunks (+b1, ReLU) -> res1T[m*128+b].
// grid 256 (m), block 128 (b): fully coalesced 512B reads per chunk.
// ---------------------------------------------------------------------------
__global__ __launch_bounds__(128, 8) void reduce_k(
    const float* __restrict__ part, const float* __restrict__ b1,
    float* __restrict__ res1T) {
    const int m = blockIdx.x, bl = threadIdx.x;
    float s = b1[m];
#pragma unroll 8
    for (int kc = 0; kc < 256; ++kc)
        s += part[(size_t)(kc * 256 + m) * B_ + bl];
    res1T[m * B_ + bl] = fmaxf(s, 0.f);
}

// ---------------------------------------------------------------------------
// Kernel 4: res2 = res1@w2.T+b2 ; out = res2@w3.T+b3. 1 block/batch row.
// ---------------------------------------------------------------------------
__global__ __launch_bounds__(512, 2) void head_k(
    const float* __restrict__ res1T, const float* __restrict__ w2,
    const float* __restrict__ b2, const float* __restrict__ w3,
    const float* __restrict__ b3, float* __restrict__ out) {
    __shared__ float r1s[256];
    __shared__ float r2s[512];
    const int tid = threadIdx.x;
    const int b   = blockIdx.x;

    if (tid < 256) r1s[tid] = res1T[tid * B_ + b];
    __syncthreads();
    {
        float s = b2[tid];
        const float* wr = &w2[tid * 256];
#pragma unroll 4
        for (int k = 0; k < 256; k += 4) {
            float4 w = *(const float4*)&wr[k];
            s += r1s[k] * w.x + r1s[k + 1] * w.y + r1s[k + 2] * w.z + r1s[k + 3] * w.w;
        }
        r2s[tid] = s;
    }
    __syncthreads();
    if (tid < 64) {
        float s = b3[tid];
        const float* wr = &w3[tid * 512];
#pragma unroll 4
        for (int k = 0; k < 512; k += 4) {
            float4 w = *(const float4*)&wr[k];
            s += r2s[k] * w.x + r2s[k + 1] * w.y + r2s[k + 2] * w.z + r2s[k + 3] * w.w;
        }
        out[b * 64 + tid] = s;
    }
}

extern "C" void kernel_launch(void* const* d_in, const int* in_sizes, int n_in,
                              void* d_out, int out_size, void* d_ws, size_t ws_size,
                              hipStream_t stream) {
    (void)in_sizes; (void)n_in; (void)out_size; (void)ws_size;
    const float* x    = (const float*)d_in[0];
    const float* w_ih = (const float*)d_in[1];
    const float* w_hh = (const float*)d_in[2];
    const float* b_ih = (const float*)d_in[3];
    const float* b_hh = (const float*)d_in[4];
    const float* w1   = (const float*)d_in[5];
    const float* b1   = (const float*)d_in[6];
    const float* w2   = (const float*)d_in[7];
    const float* b2   = (const float*)d_in[8];
    const float* w3   = (const float*)d_in[9];
    const float* b3   = (const float*)d_in[10];
    float* out = (float*)d_out;

    unsigned int* hT_p  = (unsigned int*)d_ws;                            // 65536*128*4 = 32 MB
    float*        part  = (float*)((char*)d_ws + ((size_t)32 << 20));     // 32 MB
    float*        res1T = (float*)((char*)d_ws + ((size_t)64 << 20));     // 128 KB

    const size_t smem1 = 131072 + 512 + 4096 + 4096;  // 139,776 B
    (void)hipFuncSetAttribute((const void*)lstm_k,
                              hipFuncAttributeMaxDynamicSharedMemorySize, (int)smem1);

    hipLaunchKernelGGL(lstm_k, dim3(B_), dim3(NTH), smem1, stream,
                       x, w_ih, w_hh, b_ih, b_hh, hT_p);
    hipLaunchKernelGGL(gemm1_k, dim3(4, 256), dim3(256), 0, stream, hT_p, w1, part);
    hipLaunchKernelGGL(reduce_k, dim3(256), dim3(128), 0, stream, part, b1, res1T);
    hipLaunchKernelGGL(head_k, dim3(B_), dim3(512), 0, stream,
                       res1T, w2, b2, w3, b3, out);
}

// Round 4
// 1866.047 us; speedup vs baseline: 1.6107x; 1.5922x over previous
//
#include <hip/hip_runtime.h>
#include <hip/hip_fp16.h>

#define B_    128
#define T_    1024
#define H_    256
#define NTH   512
#define NREG  96            // f16 column-pairs per row in VGPRs (cols 0..191)
#define NQR   (NREG / 4)    // 24 h-quads consumed by register part
#define NQL   8             // 8 h-quads (32 pairs, cols 192..255) in LDS

typedef _Float16 half2_t __attribute__((ext_vector_type(2)));

__device__ __forceinline__ float fdot2(unsigned int w, unsigned int h, float acc) {
    return __builtin_amdgcn_fdot2(__builtin_bit_cast(half2_t, w),
                                  __builtin_bit_cast(half2_t, h), acc, false);
}
__device__ __forceinline__ unsigned int packf16(float a, float b) {
    half2_t h;
    h.x = (_Float16)a;
    h.y = (_Float16)b;
    return __builtin_bit_cast(unsigned int, h);
}

// ---------------------------------------------------------------------------
// Kernel 1: persistent LSTM. 1 block/batch, 512 threads; thread owns gate
// rows r0=tid, r1=tid+512. 96 weight pairs/row in VGPRs (launch_bounds(.,1)
// -> 256-VGPR budget, no spill). 32 pairs/row in LDS, layout [group][row]:
// a wave's 64 lanes read 64 consecutive rows = contiguous 1KB, conflict-free.
// gates stored [gate][unit] (lane-consecutive). h packed f16 pairs in LDS.
// ---------------------------------------------------------------------------
__global__ __launch_bounds__(NTH, 1) void lstm_k(
    const float* __restrict__ x, const float* __restrict__ w_ih,
    const float* __restrict__ w_hh, const float* __restrict__ b_ih,
    const float* __restrict__ b_hh, unsigned int* __restrict__ hT_p) {
    extern __shared__ unsigned char smem[];
    uint4*        w_lds4 = (uint4*)smem;                           // [8][1024] = 128 KB
    unsigned int* h_u32  = (unsigned int*)(smem + 131072);         // [128] packed pairs
    __half*       h_half = (__half*)(smem + 131072);               // alias, [256]
    float*        gates  = (float*)(smem + 131072 + 512);          // [4][256]
    float*        xseq   = (float*)(smem + 131072 + 512 + 4096);   // [1024]

    const int tid = threadIdx.x;
    const int b   = blockIdx.x;
    const int r0  = tid, r1 = tid + NTH;
    const int u   = tid & 255;          // unit
    const int g0  = tid >> 8;           // 0:i 1:f ; r1 -> +2: g,o

    const float bs0 = b_ih[r0] + b_hh[r0], wi0 = w_ih[r0];
    const float bs1 = b_ih[r1] + b_hh[r1], wi1 = w_ih[r1];

    // xseq[t] = x[b, (t%512)*2 + t/512]
    for (int t = tid; t < T_; t += NTH)
        xseq[t] = x[b * T_ + ((t & 511) << 1) + (t >> 9)];

    // register weights: float cols [0, 192)
    unsigned int wr0[NREG], wr1[NREG];
#pragma unroll
    for (int p = 0; p < NREG; p += 2) {
        float4 a = *(const float4*)&w_hh[r0 * H_ + 2 * p];
        wr0[p] = packf16(a.x, a.y); wr0[p + 1] = packf16(a.z, a.w);
        float4 c = *(const float4*)&w_hh[r1 * H_ + 2 * p];
        wr1[p] = packf16(c.x, c.y); wr1[p + 1] = packf16(c.z, c.w);
    }
    // LDS weights: float cols [192, 256); dst = w_lds4[g*1024 + row]
    for (int idx = tid; idx < 1024 * NQL; idx += NTH) {
        int g = idx >> 10, row = idx & 1023;
        const float4* src = (const float4*)&w_hh[row * H_ + 2 * (NREG + 4 * g)];
        float4 a = src[0], c = src[1];
        uint4 pk;
        pk.x = packf16(a.x, a.y); pk.y = packf16(a.z, a.w);
        pk.z = packf16(c.x, c.y); pk.w = packf16(c.z, c.w);
        w_lds4[idx] = pk;
    }
    if (tid < 128) h_u32[tid] = 0u;
    float c_state = 0.f;
    __syncthreads();

    const uint4* h4 = (const uint4*)h_u32;

    for (int t = 0; t < T_; ++t) {
        const float xt = xseq[t];
        float a00 = fmaf(xt, wi0, bs0), a01 = 0.f;   // row r0: 2 chains
        float a10 = fmaf(xt, wi1, bs1), a11 = 0.f;   // row r1: 2 chains
#pragma unroll
        for (int q = 0; q < NQR; ++q) {
            uint4 hp = h4[q];
            a00 = fdot2(wr0[4 * q + 0], hp.x, a00);
            a01 = fdot2(wr0[4 * q + 1], hp.y, a01);
            a10 = fdot2(wr1[4 * q + 0], hp.x, a10);
            a11 = fdot2(wr1[4 * q + 1], hp.y, a11);
            a00 = fdot2(wr0[4 * q + 2], hp.z, a00);
            a01 = fdot2(wr0[4 * q + 3], hp.w, a01);
            a10 = fdot2(wr1[4 * q + 2], hp.z, a10);
            a11 = fdot2(wr1[4 * q + 3], hp.w, a11);
        }
#pragma unroll
        for (int q = 0; q < NQL; ++q) {
            uint4 hp = h4[NQR + q];
            uint4 w0 = w_lds4[(q << 10) | r0];   // contiguous per wave
            uint4 w1 = w_lds4[(q << 10) | r1];
            a00 = fdot2(w0.x, hp.x, a00);
            a01 = fdot2(w0.y, hp.y, a01);
            a10 = fdot2(w1.x, hp.x, a10);
            a11 = fdot2(w1.y, hp.y, a11);
            a00 = fdot2(w0.z, hp.z, a00);
            a01 = fdot2(w0.w, hp.w, a01);
            a10 = fdot2(w1.z, hp.z, a10);
            a11 = fdot2(w1.w, hp.w, a11);
        }
        gates[g0 * 256 + u]       = a00 + a01;   // lane-consecutive: no conflicts
        gates[(g0 + 2) * 256 + u] = a10 + a11;
        __syncthreads();
        if (tid < H_) {
            float gi = gates[tid], gf = gates[256 + tid];
            float gg = gates[512 + tid], go = gates[768 + tid];
            float i_ = __builtin_amdgcn_rcpf(1.f + __expf(-gi));
            float f_ = __builtin_amdgcn_rcpf(1.f + __expf(-gf));
            float g_ = 1.f - 2.f * __builtin_amdgcn_rcpf(__expf(2.f * gg) + 1.f);
            float o_ = __builtin_amdgcn_rcpf(1.f + __expf(-go));
            c_state = f_ * c_state + i_ * g_;
            float h = o_ * (1.f - 2.f * __builtin_amdgcn_rcpf(__expf(2.f * c_state) + 1.f));
            h_half[tid] = __float2half(h);
        }
        __syncthreads();
        if (t >= 512 && tid < 128)
            hT_p[(size_t)(((t - 512) << 7) + tid) * B_ + b] = h_u32[tid];
    }
}

// ---------------------------------------------------------------------------
// Kernel 2: res1 partials, LDS-staged. Grid (16 m-tiles, 32 k-splits),
// 256 threads. Block: rows m0..m0+15, K-slice 2048 pairs, 8 stages of 256
// pairs. w1 packed f16 in LDS [row][kp] (stride 260, 16B-aligned); reads are
// wave-uniform b128 broadcasts. h reads coalesced. part[(ks*256+m)*128+b].
// ---------------------------------------------------------------------------
#define WST 260
__global__ __launch_bounds__(256, 2) void gemm1_k(
    const unsigned int* __restrict__ hT_p, const float* __restrict__ w1,
    float* __restrict__ part) {
    __shared__ unsigned int w_stage[16 * WST];   // 16.6 KB

    const int tid = threadIdx.x;
    const int m0  = blockIdx.x * 16;
    const int ks  = blockIdx.y;                  // 0..31
    const int bl  = tid & 127;
    const int mg  = tid >> 7;                    // wave-uniform (waves 0,1 vs 2,3)
    const int srow = tid >> 4, slane = tid & 15; // staging: row, 16 lanes/row

    float acc[8];
#pragma unroll
    for (int j = 0; j < 8; ++j) acc[j] = 0.f;

    const int kbase = ks * 2048;                 // pair index base
    for (int s = 0; s < 8; ++s) {
        const int k0 = kbase + s * 256;          // this stage's 256 pairs
        __syncthreads();                         // prior reads done
        // stage w1[m0+srow][float cols 2*k0 .. 2*k0+511] as f16 pairs
        const float* wrow = &w1[(size_t)(m0 + srow) * 131072 + 2 * k0];
#pragma unroll
        for (int i = 0; i < 8; ++i) {
            const int f = slane + 16 * i;        // float4 index within row
            float4 v = *(const float4*)&wrow[4 * f];
            w_stage[srow * WST + 2 * f]     = packf16(v.x, v.y);
            w_stage[srow * WST + 2 * f + 1] = packf16(v.z, v.w);
        }
        __syncthreads();
#pragma unroll 4
        for (int kg = 0; kg < 64; ++kg) {        // 4 pairs per iter
            const int kp = 4 * kg;
            unsigned int h0 = hT_p[(size_t)(k0 + kp) * B_ + bl];
            unsigned int h1 = hT_p[(size_t)(k0 + kp + 1) * B_ + bl];
            unsigned int h2 = hT_p[(size_t)(k0 + kp + 2) * B_ + bl];
            unsigned int h3 = hT_p[(size_t)(k0 + kp + 3) * B_ + bl];
#pragma unroll
            for (int j = 0; j < 8; ++j) {
                uint4 w = *(const uint4*)&w_stage[(mg * 8 + j) * WST + kp];
                acc[j] = fdot2(w.x, h0, acc[j]);
                acc[j] = fdot2(w.y, h1, acc[j]);
                acc[j] = fdot2(w.z, h2, acc[j]);
                acc[j] = fdot2(w.w, h3, acc[j]);
            }
        }
    }
#pragma unroll
    for (int j = 0; j < 8; ++j)
        part[(size_t)(ks * 256 + m0 + mg * 8 + j) * B_ + bl] = acc[j];
}

// ---------------------------------------------------------------------------
// Kernel 3: reduce partials over 32 k-splits (+b1, ReLU) -> res1T[m*128+b].
// ---------------------------------------------------------------------------
__global__ __launch_bounds__(128, 8) void reduce_k(
    const float* __restrict__ part, const float* __restrict__ b1,
    float* __restrict__ res1T) {
    const int m = blockIdx.x, bl = threadIdx.x;
    float s = b1[m];
#pragma unroll 8
    for (int kc = 0; kc < 32; ++kc)
        s += part[(size_t)(kc * 256 + m) * B_ + bl];
    res1T[m * B_ + bl] = fmaxf(s, 0.f);
}

// ---------------------------------------------------------------------------
// Kernel 4: res2 = res1@w2.T+b2 ; out = res2@w3.T+b3. 1 block/batch row.
// ---------------------------------------------------------------------------
__global__ __launch_bounds__(512, 2) void head_k(
    const float* __restrict__ res1T, const float* __restrict__ w2,
    const float* __restrict__ b2, const float* __restrict__ w3,
    const float* __restrict__ b3, float* __restrict__ out) {
    __shared__ float r1s[256];
    __shared__ float r2s[512];
    const int tid = threadIdx.x;
    const int b   = blockIdx.x;

    if (tid < 256) r1s[tid] = res1T[tid * B_ + b];
    __syncthreads();
    {
        float s = b2[tid];
        const float* wr = &w2[tid * 256];
#pragma unroll 4
        for (int k = 0; k < 256; k += 4) {
            float4 w = *(const float4*)&wr[k];
            s += r1s[k] * w.x + r1s[k + 1] * w.y + r1s[k + 2] * w.z + r1s[k + 3] * w.w;
        }
        r2s[tid] = s;
    }
    __syncthreads();
    if (tid < 64) {
        float s = b3[tid];
        const float* wr = &w3[tid * 512];
#pragma unroll 4
        for (int k = 0; k < 512; k += 4) {
            float4 w = *(const float4*)&wr[k];
            s += r2s[k] * w.x + r2s[k + 1] * w.y + r2s[k + 2] * w.z + r2s[k + 3] * w.w;
        }
        out[b * 64 + tid] = s;
    }
}

extern "C" void kernel_launch(void* const* d_in, const int* in_sizes, int n_in,
                              void* d_out, int out_size, void* d_ws, size_t ws_size,
                              hipStream_t stream) {
    (void)in_sizes; (void)n_in; (void)out_size; (void)ws_size;
    const float* x    = (const float*)d_in[0];
    const float* w_ih = (const float*)d_in[1];
    const float* w_hh = (const float*)d_in[2];
    const float* b_ih = (const float*)d_in[3];
    const float* b_hh = (const float*)d_in[4];
    const float* w1   = (const float*)d_in[5];
    const float* b1   = (const float*)d_in[6];
    const float* w2   = (const float*)d_in[7];
    const float* b2   = (const float*)d_in[8];
    const float* w3   = (const float*)d_in[9];
    const float* b3   = (const float*)d_in[10];
    float* out = (float*)d_out;

    unsigned int* hT_p  = (unsigned int*)d_ws;                            // 65536*128*4 = 32 MB
    float*        part  = (float*)((char*)d_ws + ((size_t)32 << 20));     // 32*256*128*4 = 4 MB
    float*        res1T = (float*)((char*)d_ws + ((size_t)40 << 20));     // 128 KB

    const size_t smem1 = 131072 + 512 + 4096 + 4096;  // 139,776 B
    (void)hipFuncSetAttribute((const void*)lstm_k,
                              hipFuncAttributeMaxDynamicSharedMemorySize, (int)smem1);

    hipLaunchKernelGGL(lstm_k, dim3(B_), dim3(NTH), smem1, stream,
                       x, w_ih, w_hh, b_ih, b_hh, hT_p);
    hipLaunchKernelGGL(gemm1_k, dim3(16, 32), dim3(256), 0, stream, hT_p, w1, part);
    hipLaunchKernelGGL(reduce_k, dim3(256), dim3(128), 0, stream, part, b1, res1T);
    hipLaunchKernelGGL(head_k, dim3(B_), dim3(512), 0, stream,
                       res1T, w2, b2, w3, b3, out);
}